// Round 13
// baseline (14.102 us; speedup 1.0000x reference)
//
#include <hip/hip_runtime.h>

// Problem constants (match reference)
#define BATCH     16
#define SEQ_N     1024
#define EMBED_DIM 256
#define NTILE     16
#define STRIDEF   260   // padded row stride (floats): transpose read 2-way = free
#define REPS      3     // measurement probe: dur = F + REPS*T  (F = fixed replay
                        // overhead, T = true kernel time). R4/R9/R12 all = F + T
                        // = 10.1us despite different structure -> solve for F, T.

typedef float f32x4 __attribute__((ext_vector_type(4)));

// out[b][d][n] = embedding[seq[b][n]][d]
// R4-proven structure (10.1us), whole op repeated REPS times (idempotent:
// identical bytes each pass; memory clobber blocks cross-pass elimination).
__global__ __launch_bounds__(512) void
embed_gather_transpose(const int* __restrict__ seq,
                       const float* __restrict__ emb,
                       float* __restrict__ out) {
    __shared__ float buf[NTILE * STRIDEF];

    const int tid = threadIdx.x;
    const int b   = blockIdx.x >> 6;          // 64 tiles per batch
    const int n0  = (blockIdx.x & 63) << 4;   // *NTILE
    const int* seqb = seq + b * SEQ_N + n0;
    float*     outb = out + ((size_t)b * EMBED_DIM) * SEQ_N + n0;

    for (int r = 0; r < REPS; ++r) {
        asm volatile("" ::: "memory");  // keep every pass's loads+stores live

        // ---- load phase: 16 rows x 64 f32x4, wave-uniform 1KB row bursts ----
#pragma unroll
        for (int i = 0; i < 2; ++i) {
            const int flat = i * 512 + tid;
            const int nn   = flat >> 6;          // row in tile (wave-uniform)
            const int c4   = flat & 63;          // = lane
            const f32x4 v =
                reinterpret_cast<const f32x4*>(emb + (size_t)seqb[nn] * EMBED_DIM)[c4];
            *reinterpret_cast<f32x4*>(&buf[nn * STRIDEF + c4 * 4]) = v;
        }
        __syncthreads();

        // ---- store phase: 256 d x 4 f32x4, NT 64B chunks ----
#pragma unroll
        for (int i = 0; i < 2; ++i) {
            const int flat = i * 512 + tid;
            const int d = flat >> 2, q = flat & 3, nn = q << 2;
            f32x4 v;
            v.x = buf[(nn + 0) * STRIDEF + d];
            v.y = buf[(nn + 1) * STRIDEF + d];
            v.z = buf[(nn + 2) * STRIDEF + d];
            v.w = buf[(nn + 3) * STRIDEF + d];
            __builtin_nontemporal_store(
                v, reinterpret_cast<f32x4*>(outb + (size_t)d * SEQ_N) + q);
        }
        __syncthreads();   // tile fully stored before next pass overwrites LDS
    }
}

extern "C" void kernel_launch(void* const* d_in, const int* in_sizes, int n_in,
                              void* d_out, int out_size, void* d_ws, size_t ws_size,
                              hipStream_t stream) {
    const int*   seq = (const int*)d_in[0];
    const float* emb = (const float*)d_in[1];
    float*       out = (float*)d_out;

    const int grid = BATCH * (SEQ_N / NTILE);  // 1024 blocks
    embed_gather_transpose<<<grid, 512, 0, stream>>>(seq, emb, out);
}